// Round 8
// baseline (1176.946 us; speedup 1.0000x reference)
//
#include <hip/hip_runtime.h>
#include <math.h>

#define TT 1024
#define U1 128
#define U2 32
#define NCOL 480   // 384 rk1 gate-cols + 96 k2 cols (both dot against h1)
#define NQ 120     // long-col quads
#define NUQ 4      // u-quarters

typedef float f2 __attribute__((ext_vector_type(2)));

// v_pk_fma_f32: D = S0*S1 + S2 on 2xf32 packed (VGPR pairs).
// PK_LO: both halves multiply by h.x ; PK_HI: both halves multiply by h.y
#define PK_LO(acc, w, h) asm("v_pk_fma_f32 %0, %1, %2, %0 op_sel:[0,0,0] op_sel_hi:[1,0,1]" \
                             : "+v"(acc) : "v"(w), "v"(h))
#define PK_HI(acc, w, h) asm("v_pk_fma_f32 %0, %1, %2, %0 op_sel:[0,1,0] op_sel_hi:[1,1,1]" \
                             : "+v"(acc) : "v"(w), "v"(h))

__device__ __forceinline__ float fast_tanh(float v) {
    float e = __expf(2.f * v);      // v>>0: e=inf -> 1; v<<0: e=0 -> -1 (NaN-free)
    return 1.f - 2.f / (e + 1.f);
}
__device__ __forceinline__ float fast_sig(float v) {
    return 1.f / (1.f + __expf(-v));
}

// R7 structure (equal-best 1140us) + WEIGHT REGISTER PINNING:
//   rocprof showed VGPR_Count=92 with 128 declared weight floats -> the
//   compiler was rematerializing weight loads from L1/L2 EVERY STEP
//   (~245 KB/CU-step of cache streaming = the constant ~2670 cyc/step all
//   rounds converged to). asm volatile("":"+v"(w)) forces true residency.
// Also: h reads widened to b128 (16 reads/thread vs 32 b64).
// 256 blocks x 512 threads; block owns batches {2b, 2b+1}; 1 block/CU.
// Dot phase (t<504): thread owns 4 consecutive columns (2 f2 col-pairs) and a
//   32-long u-range; per float4 broadcast LDS read -> 8 pk (x2 batches).
//   t<480: cols 4q..4q+3 of [rk1|k2] vs h1 (u-quarter uq=t/120).
//   480<=t<504: cols of rk2 vs h2 (u=0..31 full).
// Update phase: t<256 GRU1 unit update (h_old in reg); t 256..319 GRU2
//   update lagged one step. 2 barriers/step.
__global__ __launch_bounds__(512, 1)
void gru_stack_kernel(const float* __restrict__ x,   // [512,1024,1]
                      const float* __restrict__ k1,  // [1,384]
                      const float* __restrict__ rk1, // [128,384]
                      const float* __restrict__ b1,  // [2,384]
                      const float* __restrict__ k2,  // [128,96]
                      const float* __restrict__ rk2, // [32,96]
                      const float* __restrict__ b2,  // [2,96]
                      const float* __restrict__ wd,  // [32,1]
                      const float* __restrict__ bd,  // [1]
                      float* __restrict__ out)       // [512,1]
{
    __shared__ __align__(16) float h1s[2][U1];
    __shared__ __align__(16) float h2s[2][U2];
    __shared__ __align__(16) float part1[2][NUQ][NCOL];  // [b][uq][col]
    __shared__ __align__(16) float part2[2][96];         // rk2 partials
    __shared__ __align__(16) float xs[2][TT];            // staged x rows

    const int t  = threadIdx.x;
    const int b0 = blockIdx.x * 2;

    if (t < 2 * U1) ((float*)h1s)[t] = 0.f;
    if (t < 2 * U2) ((float*)h2s)[t] = 0.f;
    for (int idx = t; idx < 2 * TT; idx += 512)          // coalesced x stage
        ((float*)xs)[idx] = x[b0 * TT + idx];

    // ---------------- dot-role setup ----------------
    f2 wA[32] = {};                     // cols {c0,c0+1} x u (32): 64 VGPRs
    f2 wB[32] = {};                     // cols {c0+2,c0+3} x u  : 64 VGPRs
    const float4* pb0 = nullptr;        // h source, batch 0 (float4 groups)
    const float4* pb1 = nullptr;        // h source, batch 1
    float4* pd0 = nullptr;              // partial dest, batch 0
    float4* pd1 = nullptr;
    const bool is_dot = (t < 504);
    if (t < 480) {
        const int uq = t / NQ, q = t % NQ;
        const int c0 = 4 * q, ub = 32 * uq;
#pragma unroll
        for (int j = 0; j < 32; ++j) {
            const int u = ub + j;
            float vv[4];
#pragma unroll
            for (int r = 0; r < 4; ++r) {
                const int c = c0 + r;
                vv[r] = (c < 384) ? rk1[u * 384 + c] : k2[u * 96 + (c - 384)];
            }
            wA[j].x = vv[0]; wA[j].y = vv[1];
            wB[j].x = vv[2]; wB[j].y = vv[3];
        }
        pb0 = (const float4*)&h1s[0][ub];
        pb1 = (const float4*)&h1s[1][ub];
        pd0 = (float4*)&part1[0][uq][c0];
        pd1 = (float4*)&part1[1][uq][c0];
    } else if (t < 504) {
        const int q2 = t - 480, c0 = 4 * q2;
#pragma unroll
        for (int j = 0; j < 32; ++j) {
            wA[j].x = rk2[j * 96 + c0 + 0]; wA[j].y = rk2[j * 96 + c0 + 1];
            wB[j].x = rk2[j * 96 + c0 + 2]; wB[j].y = rk2[j * 96 + c0 + 3];
        }
        pb0 = (const float4*)&h2s[0][0];
        pb1 = (const float4*)&h2s[1][0];
        pd0 = (float4*)&part2[0][c0];
        pd1 = (float4*)&part2[1][c0];
    }
    // ---- PIN: force weights to stay in VGPRs across the whole loop ----
#pragma unroll
    for (int j = 0; j < 32; ++j)
        asm volatile("" : "+v"(wA[j]), "+v"(wB[j]));

    // ---------------- update-role setup ----------------
    const int ju = t & 127, bu = t >> 7;               // t<256: GRU1 update
    float k1z = 0, k1r = 0, k1h = 0, bz = 0, br = 0, bhx = 0, bhr = 0, h_old = 0;
    if (t < 256) {
        k1z = k1[ju]; k1r = k1[128 + ju]; k1h = k1[256 + ju];
        bz  = b1[ju]       + b1[384 + ju];
        br  = b1[128 + ju] + b1[384 + 128 + ju];
        bhx = b1[256 + ju];
        bhr = b1[384 + 256 + ju];
    }
    const int tau = t - 256, j2 = tau & 31, bb2 = tau >> 5;  // t 256..319: GRU2 update
    float bz2 = 0, br2 = 0, bh2x = 0, bh2r = 0, h2_old = 0;
    if (t >= 256 && t < 320) {
        bz2  = b2[j2]      + b2[96 + j2];
        br2  = b2[32 + j2] + b2[96 + 32 + j2];
        bh2x = b2[64 + j2];
        bh2r = b2[96 + 64 + j2];
    }

    __syncthreads();  // B0: h init + x stage visible

    for (int i = 0; i <= TT; ++i) {
        if (is_dot) {
            f2 aA0 = {0.f, 0.f}, aB0 = {0.f, 0.f};   // batch 0: cols {c0,c0+1},{c0+2,c0+3}
            f2 aA1 = {0.f, 0.f}, aB1 = {0.f, 0.f};   // batch 1
#pragma unroll
            for (int k = 0; k < 8; ++k) {
                const float4 h0 = pb0[k];            // h[4k..4k+3] batch 0
                const float4 h1 = pb1[k];            // batch 1
                const f2 h0lo = {h0.x, h0.y}, h0hi = {h0.z, h0.w};
                const f2 h1lo = {h1.x, h1.y}, h1hi = {h1.z, h1.w};
                PK_LO(aA0, wA[4 * k],     h0lo);
                PK_HI(aA0, wA[4 * k + 1], h0lo);
                PK_LO(aA0, wA[4 * k + 2], h0hi);
                PK_HI(aA0, wA[4 * k + 3], h0hi);
                PK_LO(aB0, wB[4 * k],     h0lo);
                PK_HI(aB0, wB[4 * k + 1], h0lo);
                PK_LO(aB0, wB[4 * k + 2], h0hi);
                PK_HI(aB0, wB[4 * k + 3], h0hi);
                PK_LO(aA1, wA[4 * k],     h1lo);
                PK_HI(aA1, wA[4 * k + 1], h1lo);
                PK_LO(aA1, wA[4 * k + 2], h1hi);
                PK_HI(aA1, wA[4 * k + 3], h1hi);
                PK_LO(aB1, wB[4 * k],     h1lo);
                PK_HI(aB1, wB[4 * k + 1], h1lo);
                PK_LO(aB1, wB[4 * k + 2], h1hi);
                PK_HI(aB1, wB[4 * k + 3], h1hi);
            }
            *pd0 = make_float4(aA0.x, aA0.y, aB0.x, aB0.y);
            *pd1 = make_float4(aA1.x, aA1.y, aB1.x, aB1.y);
        }
        __syncthreads();  // B1: partials visible

        if (t < 256 && i < TT) {
            // GRU1 unit update: z/r = relu, hh = tanh (reset_after)
            const float xv = xs[bu][i];
            float iz = part1[bu][0][ju] + part1[bu][1][ju]
                     + part1[bu][2][ju] + part1[bu][3][ju];
            float ir = part1[bu][0][128 + ju] + part1[bu][1][128 + ju]
                     + part1[bu][2][128 + ju] + part1[bu][3][128 + ju];
            float ih = part1[bu][0][256 + ju] + part1[bu][1][256 + ju]
                     + part1[bu][2][256 + ju] + part1[bu][3][256 + ju];
            float z  = fmaxf(fmaf(xv, k1z, bz) + iz, 0.f);
            float r  = fmaxf(fmaf(xv, k1r, br) + ir, 0.f);
            float hh = fast_tanh(fmaf(xv, k1h, bhx) + r * (ih + bhr));
            h_old = fmaf(z, h_old - hh, hh);
            h1s[bu][ju] = h_old;
        } else if (t >= 256 && t < 320 && i >= 1) {
            // GRU2 unit update (one step behind): z/r = sigmoid, hh = relu
            float xz = part1[bb2][0][384 + j2] + part1[bb2][1][384 + j2]
                     + part1[bb2][2][384 + j2] + part1[bb2][3][384 + j2];
            float xr = part1[bb2][0][416 + j2] + part1[bb2][1][416 + j2]
                     + part1[bb2][2][416 + j2] + part1[bb2][3][416 + j2];
            float xh = part1[bb2][0][448 + j2] + part1[bb2][1][448 + j2]
                     + part1[bb2][2][448 + j2] + part1[bb2][3][448 + j2];
            float iz = part2[bb2][j2];
            float ir = part2[bb2][32 + j2];
            float ih = part2[bb2][64 + j2];
            float z  = fast_sig(xz + iz + bz2);
            float r  = fast_sig(xr + ir + br2);
            float hh = fmaxf(xh + bh2x + r * (ih + bh2r), 0.f);
            h2_old = fmaf(z, h2_old - hh, hh);
            h2s[bb2][j2] = h2_old;
        }
        __syncthreads();  // B2: h updated
    }

    // ---------------- dense head ----------------
    if (t < 64) {
        const int b = t >> 5, j = t & 31;
        float p = h2s[b][j] * wd[j];
#pragma unroll
        for (int m = 16; m >= 1; m >>= 1) p += __shfl_xor(p, m, 64);
        if (j == 0) out[b0 + b] = p + bd[0];
    }
}

extern "C" void kernel_launch(void* const* d_in, const int* in_sizes, int n_in,
                              void* d_out, int out_size, void* d_ws, size_t ws_size,
                              hipStream_t stream) {
    const float* x   = (const float*)d_in[0];
    const float* k1  = (const float*)d_in[1];
    const float* rk1 = (const float*)d_in[2];
    const float* b1  = (const float*)d_in[3];
    const float* k2  = (const float*)d_in[4];
    const float* rk2 = (const float*)d_in[5];
    const float* b2  = (const float*)d_in[6];
    const float* wd  = (const float*)d_in[7];
    const float* bd  = (const float*)d_in[8];
    float* out = (float*)d_out;

    dim3 grid(256), block(512);
    hipLaunchKernelGGL(gru_stack_kernel, grid, block, 0, stream,
                       x, k1, rk1, b1, k2, rk2, b2, wd, bd, out);
}